// Round 9
// baseline (193.090 us; speedup 1.0000x reference)
//
#include <hip/hip_runtime.h>
#include <hip/hip_bf16.h>

// ============ DIAGNOSTIC ROUND ============
// Identical to the 106.9us round-5 baseline EXCEPT grid=4096 with
// work = bid & 2047: blocks 2048..4095 duplicate the same strips and write
// identical values (benign race). Purpose: push our dispatch above the
// harness's 150us poison-fills so rocprof top-5 shows OUR counters, and
// test latency-boundness (dur < 2x => more blocks helped).

#define BATCH 64
#define CIN   16
#define H     256
#define W     256
#define HW    (H*W)
#define COUT  64
#define HO    254
#define WO    254

#define TS     16
#define TIN    18
#define CELL   24
#define NTY    8
#define NITEMS (4*TIN*TIN)
#define IPT    6

typedef short  bf16x8 __attribute__((ext_vector_type(8)));
typedef float  f32x16 __attribute__((ext_vector_type(16)));

static __device__ __forceinline__ unsigned short bfbits(float f) {
    __hip_bfloat16 h = __float2bfloat16(f);
    return *(unsigned short*)&h;
}

static __device__ __forceinline__ bf16x8 ld_frag(const ushort* p) {
    union { uint4 u; bf16x8 b; } cv;
    cv.u = *(const uint4*)p;
    return cv.b;
}

static __device__ __forceinline__ float fast_tanh(float x) {
    x = fminf(fmaxf(x, -15.f), 15.f);
    float e = __expf(2.f * x);
    return (e - 1.f) * __builtin_amdgcn_rcpf(e + 1.f);
}

__global__ void repack_w(const float* __restrict__ w, ushort* __restrict__ wpk) {
    int i = blockIdx.x * 256 + threadIdx.x;
    if (i < 9 * COUT * CIN) {
        int ci   = i & 15;
        int cout = (i >> 4) & 63;
        int tap  = i >> 10;
        wpk[i] = bfbits(w[(cout * CIN + ci) * 9 + tap]);
    }
}

__global__ __launch_bounds__(256, 2)
void conv_min_tanh_strip(const float* __restrict__ x,
                         const float* __restrict__ bias,
                         const ushort* __restrict__ wpk,
                         float* __restrict__ out) {
    __shared__ __align__(16) ushort xsm[2][TIN * TIN * CELL];

    const int bid  = blockIdx.x;            // 0..4095
    const int work = bid & 2047;            // duplicate coverage
    const int L    = (work & 7) * 256 + (work >> 3);
    const int b    = L >> 5;
    const int rr   = L & 31;
    const int yb0  = (rr >> 4) * (NTY * TS);
    const int x0   = (rr & 15) * TS;

    const int tid  = threadIdx.x;
    const int lane = tid & 63;
    const int wv   = tid >> 6;
    const int l31  = lane & 31;
    const int hi   = lane >> 5;

    const float* xp0 = x + (size_t)b * (CIN * HW);
    const float* xp1 = xp0 + HW;
    const float* xp2 = xp0 + 2 * HW;
    const float* xp3 = xp0 + 3 * HW;

    bf16x8 wf[9][2];
    #pragma unroll
    for (int tap = 0; tap < 9; ++tap)
        #pragma unroll
        for (int m = 0; m < 2; ++m)
            wf[tap][m] = ld_frag(wpk + tap * 1024 + (m * 32 + l31) * 16 + hi * 8);

    float bini[2][16];
    #pragma unroll
    for (int m = 0; m < 2; ++m)
        #pragma unroll
        for (int r = 0; r < 16; ++r)
            bini[m][r] = bias[m * 32 + (r & 3) + 8 * (r >> 2) + 4 * hi];

    // x-clamp REQUIRED (round-4 crash)
    int c0[IPT], dyv[IPT], lo[IPT];
    #pragma unroll
    for (int k = 0; k < IPT; ++k) {
        int it = tid + k * 256;
        int dx = it % TIN;
        int t2 = it / TIN;
        int dy = t2 % TIN;
        int cg = t2 / TIN;
        c0[k]  = cg * 4 * HW + min(x0 + dx, W - 1);
        dyv[k] = dy;
        lo[k]  = (dy * TIN + dx) * CELL + cg * 4;
    }

    const int py_b = wv * 4 + (l31 >> 4);
    const int pxc  = l31 & 15;
    const int cb0  = ((py_b + 0) * TIN + pxc) * CELL + hi * 8;
    const int cb1  = ((py_b + 2) * TIN + pxc) * CELL + hi * 8;

    float fx[IPT][4];

    auto stage_load = [&](int ybase) {
        #pragma unroll
        for (int k = 0; k < IPT; ++k) {
            if (k < 5 || tid < NITEMS - 5 * 256) {
                int gy  = min(ybase + dyv[k], H - 1);
                int idx = c0[k] + (gy << 8);
                fx[k][0] = xp0[idx];
                fx[k][1] = xp1[idx];
                fx[k][2] = xp2[idx];
                fx[k][3] = xp3[idx];
            }
        }
    };
    auto stage_write = [&](int buf) {
        #pragma unroll
        for (int k = 0; k < IPT; ++k) {
            if (k < 5 || tid < NITEMS - 5 * 256) {
                ushort4 v;
                v.x = bfbits(fx[k][0]);
                v.y = bfbits(fx[k][1]);
                v.z = bfbits(fx[k][2]);
                v.w = bfbits(fx[k][3]);
                *(ushort4*)&xsm[buf][lo[k]] = v;
            }
        }
    };

    stage_load(yb0);
    stage_write(0);
    __syncthreads();

    for (int t = 0; t < NTY; ++t) {
        const int cur = t & 1;

        if (t + 1 < NTY) stage_load(yb0 + (t + 1) * TS);

        f32x16 acc[2][2];
        #pragma unroll
        for (int m = 0; m < 2; ++m)
            #pragma unroll
            for (int r = 0; r < 16; ++r) {
                acc[m][0][r] = bini[m][r];
                acc[m][1][r] = bini[m][r];
            }

        const ushort* xt = &xsm[cur][0];
        #pragma unroll
        for (int tap = 0; tap < 9; ++tap) {
            const int kh = tap / 3, kw = tap - 3 * kh;
            const int toff = (kh * TIN + kw) * CELL;
            bf16x8 p0 = ld_frag(xt + cb0 + toff);
            bf16x8 p1 = ld_frag(xt + cb1 + toff);
            acc[0][0] = __builtin_amdgcn_mfma_f32_32x32x16_bf16(wf[tap][0], p0, acc[0][0], 0, 0, 0);
            acc[0][1] = __builtin_amdgcn_mfma_f32_32x32x16_bf16(wf[tap][0], p1, acc[0][1], 0, 0, 0);
            acc[1][0] = __builtin_amdgcn_mfma_f32_32x32x16_bf16(wf[tap][1], p0, acc[1][0], 0, 0, 0);
            acc[1][1] = __builtin_amdgcn_mfma_f32_32x32x16_bf16(wf[tap][1], p1, acc[1][1], 0, 0, 0);
        }

        float res[2];
        #pragma unroll
        for (int n = 0; n < 2; ++n) {
            float v[16];
            #pragma unroll
            for (int r = 0; r < 16; ++r)
                v[r] = fminf(acc[0][n][r], acc[1][n][r]);
            #pragma unroll
            for (int s = 8; s >= 1; s >>= 1)
                #pragma unroll
                for (int r = 0; r < s; ++r)
                    v[r] = fminf(v[r], v[r + s]);
            res[n] = fminf(v[0], __shfl_xor(v[0], 32, 64));
        }
        float val = hi ? res[1] : res[0];
        int px_lin = wv * 64 + lane;
        int oy = yb0 + t * TS + (px_lin >> 4);
        int ox = x0 + (px_lin & 15);
        if (oy < HO && ox < WO)
            out[((size_t)b * HO + oy) * WO + ox] = fast_tanh(fast_tanh(val));

        if (t + 1 < NTY) stage_write(cur ^ 1);
        __syncthreads();
    }
}

extern "C" void kernel_launch(void* const* d_in, const int* in_sizes, int n_in,
                              void* d_out, int out_size, void* d_ws, size_t ws_size,
                              hipStream_t stream) {
    const float* x    = (const float*)d_in[0];
    const float* w    = (const float*)d_in[1];
    const float* bias = (const float*)d_in[2];
    float* out        = (float*)d_out;
    ushort* wpk       = (ushort*)d_ws;

    hipLaunchKernelGGL(repack_w, dim3(36), dim3(256), 0, stream, w, wpk);
    hipLaunchKernelGGL(conv_min_tanh_strip, dim3(4096), dim3(256), 0, stream,
                       x, bias, wpk, out);
}